// Round 5
// baseline (676.461 us; speedup 1.0000x reference)
//
#include <hip/hip_runtime.h>
#include <hip/hip_bf16.h>
#include <stdint.h>

#define M_DIM 16384   // B*S = 4*4096
#define N_DIM 4096    // OUT
#define K_DIM 4096    // IN
#define NT    (K_DIM / 64)   // 64 K-tiles of BK=64

typedef float f32x4  __attribute__((ext_vector_type(4)));
typedef float f32x16 __attribute__((ext_vector_type(16)));
typedef short bf16x8 __attribute__((ext_vector_type(8)));
typedef unsigned short u16;

__device__ __forceinline__ unsigned short f32_to_bf16(float f) {
    union { float f; uint32_t u; } v; v.f = f;
    uint32_t u = v.u;
    uint32_t r = (u + 0x7FFFu + ((u >> 16) & 1u)) >> 16;   // RNE
    return (unsigned short)r;
}

__device__ __forceinline__ void gload16(const void* g, void* l) {
    __builtin_amdgcn_global_load_lds(
        (const __attribute__((address_space(1))) void*)g,
        (__attribute__((address_space(3))) void*)l,
        16, 0, 0);
}

// ---------------------------------------------------------------------------
// Fused prep: blocks [0,16384): Weff build; blocks [16384,49152): x cvt.
// Weff[o][i] = bf16( W0[o][i] + 0.25 * w1[o>>6][i>>6] * w2[o&63][i&63] )
// ---------------------------------------------------------------------------
__global__ void prep(const float* __restrict__ W0,
                     const float* __restrict__ w1,
                     const float* __restrict__ w2a,
                     const float* __restrict__ w2b,
                     const float* __restrict__ x,
                     u16* __restrict__ Weff,
                     u16* __restrict__ xb) {
    const int bid = blockIdx.x;
    if (bid < 16384) {
        long idx = (long)bid * 256 + threadIdx.x;   // over N*K/4
        long e0 = idx * 4;
        int o  = (int)(e0 >> 12);
        int i0 = (int)(e0 & 4095);
        int r  = o & 63;
        float a0 = w2a[r * 4 + 0], a1 = w2a[r * 4 + 1];
        float a2 = w2a[r * 4 + 2], a3 = w2a[r * 4 + 3];
        float w1v = w1[(o >> 6) * 64 + (i0 >> 6)] * 0.25f;
        float4 w0 = *(const float4*)(W0 + e0);
        const float* w0p = (const float*)&w0;
        unsigned short outp[4];
#pragma unroll
        for (int j = 0; j < 4; ++j) {
            int c = (i0 + j) & 63;
            float w2 = a0 * w2b[0 * 64 + c] + a1 * w2b[1 * 64 + c]
                     + a2 * w2b[2 * 64 + c] + a3 * w2b[3 * 64 + c];
            outp[j] = f32_to_bf16(w0p[j] + w1v * w2);
        }
        *(ushort4*)(Weff + e0) = make_ushort4(outp[0], outp[1], outp[2], outp[3]);
    } else {
        long idx = (long)(bid - 16384) * 256 + threadIdx.x;   // over M*K/8
        long e0 = idx * 8;
        float4 v0 = *(const float4*)(x + e0);
        float4 v1 = *(const float4*)(x + e0 + 4);
        union { unsigned short s[8]; int4 v; } o;
        const float* p0 = (const float*)&v0;
        const float* p1 = (const float*)&v1;
#pragma unroll
        for (int j = 0; j < 4; ++j) o.s[j]     = f32_to_bf16(p0[j]);
#pragma unroll
        for (int j = 0; j < 4; ++j) o.s[4 + j] = f32_to_bf16(p1[j]);
        *(int4*)(xb + e0) = o.v;
    }
}

// ---------------------------------------------------------------------------
// GEMM: 256x256 tile, BK=64, 8 waves (2Mx4N), 32x32x16 MFMA.
// Phase = (buf, kslice, n-half): odd phases read 8 A + 2 B frags + stage,
// even phases read 2 B frags; vmcnt(8) gates at even-phase ends.
// C[m][o] = sum_k A[m][k]*B[o][k] + bias[o]
// ---------------------------------------------------------------------------
__global__ __launch_bounds__(512, 2) void gemm_8p(
        const u16* __restrict__ A,    // M x K bf16
        const u16* __restrict__ Bm,   // N x K bf16 (B^T)
        const float* __restrict__ bias,
        float* __restrict__ C) {
    // [buf][kslice][256 rows][32 cols] bf16, 16KB per (buf,kslice) region
    __shared__ __align__(16) u16 ldsA[2][2][8192];
    __shared__ __align__(16) u16 ldsB[2][2][8192];

    const int tid = threadIdx.x;
    const int bid = blockIdx.x;
    // bijective XCD swizzle (nwg = 1024, %8==0)
    const int swz = (bid & 7) * 128 + (bid >> 3);
    const int tm = swz >> 4;          // 64 M-tiles
    const int tn = swz & 15;          // 16 N-tiles
    const int mBase = tm * 256;
    const int nBase = tn * 256;

    const int lane = tid & 63;
    const int wave = tid >> 6;
    const int wr = wave >> 2;         // 0..1  (M half)
    const int wc = wave & 3;          // 0..3  (N quarter)

    // ---- staging (write side): linear LDS dest, inverse-swizzled source ----
    const int srow = tid >> 2;                        // 0..127
    const int slog = (tid & 3) ^ ((srow >> 1) & 3);   // logical 16B slot
    const u16* aS0 = A  + (size_t)(mBase + srow)       * K_DIM + slog * 8;
    const u16* aS1 = A  + (size_t)(mBase + srow + 128) * K_DIM + slog * 8;
    const u16* bS0 = Bm + (size_t)(nBase + srow)       * K_DIM + slog * 8;
    const u16* bS1 = Bm + (size_t)(nBase + srow + 128) * K_DIM + slog * 8;

#define STAGE_A(buf, t, ks) do { const size_t _k = (size_t)(t) * 64 + (ks) * 32; \
        gload16(aS0 + _k, &ldsA[buf][ks][tid * 8]);                              \
        gload16(aS1 + _k, &ldsA[buf][ks][4096 + tid * 8]); } while (0)
#define STAGE_B(buf, t, ks) do { const size_t _k = (size_t)(t) * 64 + (ks) * 32; \
        gload16(bS0 + _k, &ldsB[buf][ks][tid * 8]);                              \
        gload16(bS1 + _k, &ldsB[buf][ks][4096 + tid * 8]); } while (0)

    // ---- fragment read bases (swizzled), 32x32x16 operand layout ----
    // lane: row-in-tile = lane&31, k-group g = lane>>5 (8 consecutive k each)
    const int rl32 = lane & 31, g = lane >> 5;
    const int rowA0 = wr * 128 + rl32;                 // + mi*32
    const int rowB0 = wc * 64 + rl32;                  // + nh*32
    const int swA = (rowA0 >> 1) & 3;                  // invariant across mi
    const int swB = (rowB0 >> 1) & 3;                  // invariant across nh
    const int aBase = rowA0 * 32;
    const int bBase = rowB0 * 32;
    const int sa0 = ((0 + g) ^ swA) * 8, sa1 = ((2 + g) ^ swA) * 8;
    const int sb0 = ((0 + g) ^ swB) * 8, sb1 = ((2 + g) ^ swB) * 8;

#define RD_A(buf, ks, mi, sk) (*(const bf16x8*)&ldsA[buf][ks][aBase + (mi) * 1024 + (sk)])
#define RD_B(buf, ks, nh, sk) (*(const bf16x8*)&ldsB[buf][ks][bBase + (nh) * 1024 + (sk)])

    // accumulators: 4 m-tiles x 2 n-halves, f32x16 each (AGPR)
    f32x16 acc00 = {}, acc01 = {}, acc10 = {}, acc11 = {};
    f32x16 acc20 = {}, acc21 = {}, acc30 = {}, acc31 = {};
    bf16x8 a00, a01, a10, a11, a20, a21, a30, a31;   // A frags: mi x k16
    bf16x8 b0, b1;                                   // B frags: k16 0/1

#define MFMA8(AC0, AC1, AC2, AC3)                                              \
    AC0 = __builtin_amdgcn_mfma_f32_32x32x16_bf16(a00, b0, AC0, 0, 0, 0);      \
    AC1 = __builtin_amdgcn_mfma_f32_32x32x16_bf16(a10, b0, AC1, 0, 0, 0);      \
    AC2 = __builtin_amdgcn_mfma_f32_32x32x16_bf16(a20, b0, AC2, 0, 0, 0);      \
    AC3 = __builtin_amdgcn_mfma_f32_32x32x16_bf16(a30, b0, AC3, 0, 0, 0);      \
    AC0 = __builtin_amdgcn_mfma_f32_32x32x16_bf16(a01, b1, AC0, 0, 0, 0);      \
    AC1 = __builtin_amdgcn_mfma_f32_32x32x16_bf16(a11, b1, AC1, 0, 0, 0);      \
    AC2 = __builtin_amdgcn_mfma_f32_32x32x16_bf16(a21, b1, AC2, 0, 0, 0);      \
    AC3 = __builtin_amdgcn_mfma_f32_32x32x16_bf16(a31, b1, AC3, 0, 0, 0);

    // odd phase: (buf,ks,nh=0) — reads 2 B + 8 A, stage, MFMA n-half 0
#define PH_N0(buf, ks, ...) do {                                        \
        __builtin_amdgcn_s_barrier();                                   \
        b0  = RD_B(buf, ks, 0, sb0); b1  = RD_B(buf, ks, 0, sb1);       \
        a00 = RD_A(buf, ks, 0, sa0); a01 = RD_A(buf, ks, 0, sa1);       \
        a10 = RD_A(buf, ks, 1, sa0); a11 = RD_A(buf, ks, 1, sa1);       \
        a20 = RD_A(buf, ks, 2, sa0); a21 = RD_A(buf, ks, 2, sa1);       \
        a30 = RD_A(buf, ks, 3, sa0); a31 = RD_A(buf, ks, 3, sa1);       \
        __VA_ARGS__;                                                    \
        __builtin_amdgcn_s_setprio(1);                                  \
        MFMA8(acc00, acc10, acc20, acc30)                               \
        __builtin_amdgcn_s_setprio(0);                                  \
        __builtin_amdgcn_sched_barrier(0);                              \
    } while (0)
    // even phase: (buf,ks,nh=1) — reads 2 B, MFMA n-half 1, vmcnt(8) gate
#define PH_N1(buf, ks) do {                                             \
        __builtin_amdgcn_s_barrier();                                   \
        b0  = RD_B(buf, ks, 1, sb0); b1  = RD_B(buf, ks, 1, sb1);       \
        __builtin_amdgcn_s_setprio(1);                                  \
        MFMA8(acc01, acc11, acc21, acc31)                               \
        __builtin_amdgcn_s_setprio(0);                                  \
        __builtin_amdgcn_sched_barrier(0);                              \
        asm volatile("s_waitcnt vmcnt(8)" ::: "memory");                \
    } while (0)

    // ---- prologue: buf0 full (t0, 8 loads) + buf1ks0 (t1, 4 loads) ----
    STAGE_B(0, 0, 0); STAGE_A(0, 0, 0); STAGE_B(0, 0, 1); STAGE_A(0, 0, 1);
    STAGE_B(1, 1, 0); STAGE_A(1, 1, 0);
    asm volatile("s_waitcnt vmcnt(4)" ::: "memory");   // buf0 complete

    // ---- main loop: 32 iterations x 2 K-tiles, 8 phases each ----
    for (int it = 0; it < NT / 2; ++it) {
        const int t1 = 2 * it + 1;
        const int t2 = (2 * it + 2 < NT) ? 2 * it + 2 : NT - 1;
        const int t3 = (2 * it + 3 < NT) ? 2 * it + 3 : NT - 1;
        PH_N0(0, 0, STAGE_B(1, t1, 1); STAGE_A(1, t1, 1));   // P1
        PH_N1(0, 0);                                         // P2 gate
        PH_N0(0, 1, STAGE_B(0, t2, 0); STAGE_A(0, t2, 0));   // P3
        PH_N1(0, 1);                                         // P4 gate
        PH_N0(1, 0, STAGE_B(0, t2, 1); STAGE_A(0, t2, 1));   // P5
        PH_N1(1, 0);                                         // P6 gate
        PH_N0(1, 1, STAGE_B(1, t3, 0); STAGE_A(1, t3, 0));   // P7
        PH_N1(1, 1);                                         // P8 gate
    }
    asm volatile("s_waitcnt vmcnt(0) lgkmcnt(0)" ::: "memory");

    // ---- epilogue: 32x32 C/D: col=lane&31, row=(r&3)+8*(r>>2)+4*(lane>>5) ----
#define STORE_T(ACC, mi, nh) do {                                              \
        const int col = nBase + wc * 64 + (nh) * 32 + rl32;                    \
        const float bv = bias[col];                                            \
        _Pragma("unroll")                                                      \
        for (int r = 0; r < 16; ++r) {                                         \
            const int row = mBase + wr * 128 + (mi) * 32 +                     \
                            (r & 3) + 8 * (r >> 2) + 4 * g;                    \
            C[(size_t)row * N_DIM + col] = ACC[r] + bv;                        \
        }                                                                      \
    } while (0)
    STORE_T(acc00, 0, 0); STORE_T(acc01, 0, 1);
    STORE_T(acc10, 1, 0); STORE_T(acc11, 1, 1);
    STORE_T(acc20, 2, 0); STORE_T(acc21, 2, 1);
    STORE_T(acc30, 3, 0); STORE_T(acc31, 3, 1);
#undef STAGE_A
#undef STAGE_B
#undef RD_A
#undef RD_B
#undef MFMA8
#undef PH_N0
#undef PH_N1
#undef STORE_T
}

// ---------------------------------------------------------------------------
// Fallback (only if ws_size too small): correct but slow
// ---------------------------------------------------------------------------
__global__ void naive_fallback(const float* __restrict__ x,
                               const float* __restrict__ W0,
                               const float* __restrict__ b,
                               const float* __restrict__ w1,
                               const float* __restrict__ w2a,
                               const float* __restrict__ w2b,
                               float* __restrict__ out) {
    __shared__ float w2s[64 * 64];
    for (int t = threadIdx.x; t < 4096; t += blockDim.x) {
        int rr = t >> 6, cc = t & 63;
        float s = 0.f;
        for (int k = 0; k < 4; ++k) s += w2a[rr * 4 + k] * w2b[k * 64 + cc];
        w2s[t] = s * 0.25f;
    }
    __syncthreads();
    long idx = (long)blockIdx.x * blockDim.x + threadIdx.x;
    int m = (int)(idx >> 12);
    int o = (int)(idx & 4095);
    const float* xr = x + (long)m * K_DIM;
    const float* wrp = W0 + (long)o * K_DIM;
    int ob = (o >> 6) * 64, orr = (o & 63) * 64;
    float acc = 0.f;
    for (int i = 0; i < K_DIM; ++i) {
        float w = wrp[i] + w1[ob + (i >> 6)] * w2s[orr + (i & 63)];
        acc += xr[i] * w;
    }
    out[idx] = acc + b[o];
}

extern "C" void kernel_launch(void* const* d_in, const int* in_sizes, int n_in,
                              void* d_out, int out_size, void* d_ws, size_t ws_size,
                              hipStream_t stream) {
    const float* x   = (const float*)d_in[0];
    const float* W0  = (const float*)d_in[1];
    const float* b   = (const float*)d_in[2];
    const float* w1  = (const float*)d_in[3];
    const float* w2a = (const float*)d_in[4];
    const float* w2b = (const float*)d_in[5];
    float* out = (float*)d_out;

    const size_t xb_bytes = (size_t)M_DIM * K_DIM * 2;   // 128 MB
    const size_t wf_bytes = (size_t)N_DIM * K_DIM * 2;   // 32 MB

    if (ws_size >= xb_bytes + wf_bytes) {
        u16* xb = (u16*)d_ws;
        u16* wf = (u16*)((char*)d_ws + xb_bytes);
        prep<<<49152, 256, 0, stream>>>(W0, w1, w2a, w2b, x, wf, xb);
        gemm_8p<<<(M_DIM / 256) * (N_DIM / 256), 512, 0, stream>>>(xb, wf, b, out);
    } else {
        naive_fallback<<<((long)M_DIM * N_DIM) / 256, 256, 0, stream>>>(
            x, W0, b, w1, w2a, w2b, out);
    }
}

// Round 6
// 648.252 us; speedup vs baseline: 1.0435x; 1.0435x over previous
//
#include <hip/hip_runtime.h>
#include <hip/hip_bf16.h>
#include <stdint.h>

#define M_DIM 16384   // B*S = 4*4096
#define N_DIM 4096    // OUT
#define K_DIM 4096    // IN
#define NT    (K_DIM / 64)   // 64 K-tiles of BK=64

typedef float f32x4  __attribute__((ext_vector_type(4)));
typedef short bf16x8 __attribute__((ext_vector_type(8)));
typedef unsigned short u16;

__device__ __forceinline__ unsigned short f32_to_bf16(float f) {
    union { float f; uint32_t u; } v; v.f = f;
    uint32_t u = v.u;
    uint32_t r = (u + 0x7FFFu + ((u >> 16) & 1u)) >> 16;   // RNE
    return (unsigned short)r;
}

__device__ __forceinline__ void gload16(const void* g, void* l) {
    __builtin_amdgcn_global_load_lds(
        (const __attribute__((address_space(1))) void*)g,
        (__attribute__((address_space(3))) void*)l,
        16, 0, 0);
}

// ---------------------------------------------------------------------------
// Fused prep: blocks [0,16384): Weff build; blocks [16384,49152): x cvt.
// Weff[o][i] = bf16( W0[o][i] + 0.25 * w1[o>>6][i>>6] * w2[o&63][i&63] )
// ---------------------------------------------------------------------------
__global__ void prep(const float* __restrict__ W0,
                     const float* __restrict__ w1,
                     const float* __restrict__ w2a,
                     const float* __restrict__ w2b,
                     const float* __restrict__ x,
                     u16* __restrict__ Weff,
                     u16* __restrict__ xb) {
    const int bid = blockIdx.x;
    if (bid < 16384) {
        long idx = (long)bid * 256 + threadIdx.x;   // over N*K/4
        long e0 = idx * 4;
        int o  = (int)(e0 >> 12);
        int i0 = (int)(e0 & 4095);
        int r  = o & 63;
        float a0 = w2a[r * 4 + 0], a1 = w2a[r * 4 + 1];
        float a2 = w2a[r * 4 + 2], a3 = w2a[r * 4 + 3];
        float w1v = w1[(o >> 6) * 64 + (i0 >> 6)] * 0.25f;
        float4 w0 = *(const float4*)(W0 + e0);
        const float* w0p = (const float*)&w0;
        unsigned short outp[4];
#pragma unroll
        for (int j = 0; j < 4; ++j) {
            int c = (i0 + j) & 63;
            float w2 = a0 * w2b[0 * 64 + c] + a1 * w2b[1 * 64 + c]
                     + a2 * w2b[2 * 64 + c] + a3 * w2b[3 * 64 + c];
            outp[j] = f32_to_bf16(w0p[j] + w1v * w2);
        }
        *(ushort4*)(Weff + e0) = make_ushort4(outp[0], outp[1], outp[2], outp[3]);
    } else {
        long idx = (long)(bid - 16384) * 256 + threadIdx.x;   // over M*K/8
        long e0 = idx * 8;
        float4 v0 = *(const float4*)(x + e0);
        float4 v1 = *(const float4*)(x + e0 + 4);
        union { unsigned short s[8]; int4 v; } o;
        const float* p0 = (const float*)&v0;
        const float* p1 = (const float*)&v1;
#pragma unroll
        for (int j = 0; j < 4; ++j) o.s[j]     = f32_to_bf16(p0[j]);
#pragma unroll
        for (int j = 0; j < 4; ++j) o.s[4 + j] = f32_to_bf16(p1[j]);
        *(int4*)(xb + e0) = o.v;
    }
}

// ---------------------------------------------------------------------------
// GEMM: 256x256 tile, BK=64, 8 waves (2Mx4N), 16x16x32 MFMA.
// QUADRANT phasing (m201-style): per K-tile 4 phases, each = one C-quadrant
// over full K=64. Reads/phase: {12, 4, 8, 0}; A/B frags reused across phases
// from registers. One barrier per phase; vmcnt(4) gate once per tile.
// C[m][o] = sum_k A[m][k]*B[o][k] + bias[o]
// ---------------------------------------------------------------------------
__global__ __launch_bounds__(512, 2) void gemm_q(
        const u16* __restrict__ A,    // M x K bf16
        const u16* __restrict__ Bm,   // N x K bf16 (B^T)
        const float* __restrict__ bias,
        float* __restrict__ C) {
    // [buf][kslice][256 rows][32 cols] bf16, 16KB per (buf,kslice) region
    __shared__ __align__(16) u16 ldsA[2][2][8192];
    __shared__ __align__(16) u16 ldsB[2][2][8192];

    const int tid = threadIdx.x;
    const int bid = blockIdx.x;
    // bijective XCD swizzle (nwg = 1024, %8==0)
    const int swz = (bid & 7) * 128 + (bid >> 3);
    const int tm = swz >> 4;          // 64 M-tiles
    const int tn = swz & 15;          // 16 N-tiles
    const int mBase = tm * 256;
    const int nBase = tn * 256;

    const int lane = tid & 63;
    const int wave = tid >> 6;
    const int wr = wave >> 2;         // 0..1  (M half)
    const int wc = wave & 3;          // 0..3  (N quarter)

    // ---- staging (write side): linear LDS dest, inverse-swizzled source ----
    const int srow = tid >> 2;                        // 0..127
    const int slog = (tid & 3) ^ ((srow >> 1) & 3);   // logical 16B slot
    const u16* aS0 = A  + (size_t)(mBase + srow)       * K_DIM + slog * 8;
    const u16* aS1 = A  + (size_t)(mBase + srow + 128) * K_DIM + slog * 8;
    const u16* bS0 = Bm + (size_t)(nBase + srow)       * K_DIM + slog * 8;
    const u16* bS1 = Bm + (size_t)(nBase + srow + 128) * K_DIM + slog * 8;

#define STAGE_A(buf, t, ks) do { const size_t _k = (size_t)(t) * 64 + (ks) * 32; \
        gload16(aS0 + _k, &ldsA[buf][ks][tid * 8]);                              \
        gload16(aS1 + _k, &ldsA[buf][ks][4096 + tid * 8]); } while (0)
#define STAGE_B(buf, t, ks) do { const size_t _k = (size_t)(t) * 64 + (ks) * 32; \
        gload16(bS0 + _k, &ldsB[buf][ks][tid * 8]);                              \
        gload16(bS1 + _k, &ldsB[buf][ks][4096 + tid * 8]); } while (0)

    // ---- fragment read bases (swizzled) — proven conflict-free pattern ----
    const int rl = lane & 15, cbk = lane >> 4;        // row-in-frag, k-group
    const int sslot = cbk ^ ((rl >> 1) & 3);
    const int aRd = (wr * 128 + rl) * 32 + sslot * 8;  // ushort offset
    const int bRd = (wc * 64  + rl) * 32 + sslot * 8;

#define RD_A(buf, ks, m) (*(const bf16x8*)&ldsA[buf][ks][aRd + (m) * 512])
#define RD_B(buf, ks, n) (*(const bf16x8*)&ldsB[buf][ks][bRd + (n) * 512])

    f32x4 acc[8][4] = {};
    bf16x8 af[4][2];   // A frags: 4 m x 2 kk (holds m-lo, then m-hi)
    bf16x8 bL[2][2];   // B frags n-lo: n{0,1} x kk
    bf16x8 bH[2][2];   // B frags n-hi: n{2,3} x kk

    // quadrant MFMA: 16 = kk-outer x 4m x 2n (dep distance 8)
#define QUAD(mh, nh, BREG)                                                     \
    _Pragma("unroll")                                                          \
    for (int kk = 0; kk < 2; ++kk) {                                           \
        _Pragma("unroll")                                                      \
        for (int m = 0; m < 4; ++m) {                                          \
            _Pragma("unroll")                                                  \
            for (int n = 0; n < 2; ++n)                                        \
                acc[(mh)*4+m][(nh)*2+n] = __builtin_amdgcn_mfma_f32_16x16x32_bf16( \
                    af[m][kk], BREG[n][kk], acc[(mh)*4+m][(nh)*2+n], 0, 0, 0); \
        }                                                                      \
    }

#define PH_TOP() __builtin_amdgcn_s_barrier()
#define PH_BOT() __builtin_amdgcn_sched_barrier(0)

    // ---------- prologue ----------
    // order matters for vmcnt ledger: B(0) x2, A(0) x2, B(1) x2  (12 loads)
    STAGE_B(0, 0, 0); STAGE_B(0, 0, 1);
    STAGE_A(0, 0, 0); STAGE_A(0, 0, 1);
    STAGE_B(1, 1, 0); STAGE_B(1, 1, 1);
    asm volatile("s_waitcnt vmcnt(4)" ::: "memory");   // tile0 A+B complete

    // ---------- main loop: NT/2 iters x 2 tiles x 4 phases ----------
    for (int it = 0; it < NT / 2; ++it) {
        const int u1 = 2 * it + 1;
        const int t2 = (2 * it + 2 < NT) ? 2 * it + 2 : NT - 1;
        const int t3 = (2 * it + 3 < NT) ? 2 * it + 3 : NT - 1;

        // ===== tile u0 = 2it, buf 0 =====
        // PhA: reads B-lo(4) + A-lo(8); stage A(u1 -> buf1, ks0)
        PH_TOP();
        bL[0][0] = RD_B(0, 0, 0); bL[0][1] = RD_B(0, 1, 0);
        bL[1][0] = RD_B(0, 0, 1); bL[1][1] = RD_B(0, 1, 1);
        af[0][0] = RD_A(0, 0, 0); af[0][1] = RD_A(0, 1, 0);
        af[1][0] = RD_A(0, 0, 1); af[1][1] = RD_A(0, 1, 1);
        af[2][0] = RD_A(0, 0, 2); af[2][1] = RD_A(0, 1, 2);
        af[3][0] = RD_A(0, 0, 3); af[3][1] = RD_A(0, 1, 3);
        STAGE_A(1, u1, 0);
        __builtin_amdgcn_s_setprio(1);
        QUAD(0, 0, bL)
        __builtin_amdgcn_s_setprio(0);
        PH_BOT();
        // PhB: reads B-hi(4); stage A(u1 -> buf1, ks1)
        PH_TOP();
        bH[0][0] = RD_B(0, 0, 2); bH[0][1] = RD_B(0, 1, 2);
        bH[1][0] = RD_B(0, 0, 3); bH[1][1] = RD_B(0, 1, 3);
        STAGE_A(1, u1, 1);
        __builtin_amdgcn_s_setprio(1);
        QUAD(0, 1, bH)
        __builtin_amdgcn_s_setprio(0);
        PH_BOT();
        // PhC: reads A-hi(8); stage B(t2 -> buf0, ks0)
        PH_TOP();
        af[0][0] = RD_A(0, 0, 4); af[0][1] = RD_A(0, 1, 4);
        af[1][0] = RD_A(0, 0, 5); af[1][1] = RD_A(0, 1, 5);
        af[2][0] = RD_A(0, 0, 6); af[2][1] = RD_A(0, 1, 6);
        af[3][0] = RD_A(0, 0, 7); af[3][1] = RD_A(0, 1, 7);
        STAGE_B(0, t2, 0);
        __builtin_amdgcn_s_setprio(1);
        QUAD(1, 0, bL)
        __builtin_amdgcn_s_setprio(0);
        PH_BOT();
        // PhD: no reads; stage B(t2 -> buf0, ks1); gate tile u1
        PH_TOP();
        STAGE_B(0, t2, 1);
        __builtin_amdgcn_s_setprio(1);
        QUAD(1, 1, bH)
        __builtin_amdgcn_s_setprio(0);
        asm volatile("s_waitcnt vmcnt(4)" ::: "memory");   // A(u1),B(u1) done
        PH_BOT();

        // ===== tile u1 = 2it+1, buf 1 =====
        // PhA: reads; stage A(t2 -> buf0, ks0)
        PH_TOP();
        bL[0][0] = RD_B(1, 0, 0); bL[0][1] = RD_B(1, 1, 0);
        bL[1][0] = RD_B(1, 0, 1); bL[1][1] = RD_B(1, 1, 1);
        af[0][0] = RD_A(1, 0, 0); af[0][1] = RD_A(1, 1, 0);
        af[1][0] = RD_A(1, 0, 1); af[1][1] = RD_A(1, 1, 1);
        af[2][0] = RD_A(1, 0, 2); af[2][1] = RD_A(1, 1, 2);
        af[3][0] = RD_A(1, 0, 3); af[3][1] = RD_A(1, 1, 3);
        STAGE_A(0, t2, 0);
        __builtin_amdgcn_s_setprio(1);
        QUAD(0, 0, bL)
        __builtin_amdgcn_s_setprio(0);
        PH_BOT();
        // PhB: reads B-hi; stage A(t2 -> buf0, ks1)
        PH_TOP();
        bH[0][0] = RD_B(1, 0, 2); bH[0][1] = RD_B(1, 1, 2);
        bH[1][0] = RD_B(1, 0, 3); bH[1][1] = RD_B(1, 1, 3);
        STAGE_A(0, t2, 1);
        __builtin_amdgcn_s_setprio(1);
        QUAD(0, 1, bH)
        __builtin_amdgcn_s_setprio(0);
        PH_BOT();
        // PhC: reads A-hi; stage B(t3 -> buf1, ks0)
        PH_TOP();
        af[0][0] = RD_A(1, 0, 4); af[0][1] = RD_A(1, 1, 4);
        af[1][0] = RD_A(1, 0, 5); af[1][1] = RD_A(1, 1, 5);
        af[2][0] = RD_A(1, 0, 6); af[2][1] = RD_A(1, 1, 6);
        af[3][0] = RD_A(1, 0, 7); af[3][1] = RD_A(1, 1, 7);
        STAGE_B(1, t3, 0);
        __builtin_amdgcn_s_setprio(1);
        QUAD(1, 0, bL)
        __builtin_amdgcn_s_setprio(0);
        PH_BOT();
        // PhD: no reads; stage B(t3 -> buf1, ks1); gate tile t2
        PH_TOP();
        STAGE_B(1, t3, 1);
        __builtin_amdgcn_s_setprio(1);
        QUAD(1, 1, bH)
        __builtin_amdgcn_s_setprio(0);
        asm volatile("s_waitcnt vmcnt(4)" ::: "memory");   // A(t2),B(t2) done
        PH_BOT();
    }
    asm volatile("s_waitcnt vmcnt(0) lgkmcnt(0)" ::: "memory");

    // ---- epilogue: C/D layout col=lane&15, row=(lane>>4)*4+j ----
#pragma unroll
    for (int n = 0; n < 4; ++n) {
        const int col = nBase + wc * 64 + n * 16 + rl;
        const float bv = bias[col];
#pragma unroll
        for (int m = 0; m < 8; ++m) {
            const int row = mBase + wr * 128 + m * 16 + cbk * 4;
#pragma unroll
            for (int j = 0; j < 4; ++j)
                C[(size_t)(row + j) * N_DIM + col] = acc[m][n][j] + bv;
        }
    }
#undef STAGE_A
#undef STAGE_B
#undef RD_A
#undef RD_B
#undef QUAD
#undef PH_TOP
#undef PH_BOT
}

// ---------------------------------------------------------------------------
// Fallback (only if ws_size too small): correct but slow
// ---------------------------------------------------------------------------
__global__ void naive_fallback(const float* __restrict__ x,
                               const float* __restrict__ W0,
                               const float* __restrict__ b,
                               const float* __restrict__ w1,
                               const float* __restrict__ w2a,
                               const float* __restrict__ w2b,
                               float* __restrict__ out) {
    __shared__ float w2s[64 * 64];
    for (int t = threadIdx.x; t < 4096; t += blockDim.x) {
        int rr = t >> 6, cc = t & 63;
        float s = 0.f;
        for (int k = 0; k < 4; ++k) s += w2a[rr * 4 + k] * w2b[k * 64 + cc];
        w2s[t] = s * 0.25f;
    }
    __syncthreads();
    long idx = (long)blockIdx.x * blockDim.x + threadIdx.x;
    int m = (int)(idx >> 12);
    int o = (int)(idx & 4095);
    const float* xr = x + (long)m * K_DIM;
    const float* wrp = W0 + (long)o * K_DIM;
    int ob = (o >> 6) * 64, orr = (o & 63) * 64;
    float acc = 0.f;
    for (int i = 0; i < K_DIM; ++i) {
        float w = wrp[i] + w1[ob + (i >> 6)] * w2s[orr + (i & 63)];
        acc += xr[i] * w;
    }
    out[idx] = acc + b[o];
}

extern "C" void kernel_launch(void* const* d_in, const int* in_sizes, int n_in,
                              void* d_out, int out_size, void* d_ws, size_t ws_size,
                              hipStream_t stream) {
    const float* x   = (const float*)d_in[0];
    const float* W0  = (const float*)d_in[1];
    const float* b   = (const float*)d_in[2];
    const float* w1  = (const float*)d_in[3];
    const float* w2a = (const float*)d_in[4];
    const float* w2b = (const float*)d_in[5];
    float* out = (float*)d_out;

    const size_t xb_bytes = (size_t)M_DIM * K_DIM * 2;   // 128 MB
    const size_t wf_bytes = (size_t)N_DIM * K_DIM * 2;   // 32 MB

    if (ws_size >= xb_bytes + wf_bytes) {
        u16* xb = (u16*)d_ws;
        u16* wf = (u16*)((char*)d_ws + xb_bytes);
        prep<<<49152, 256, 0, stream>>>(W0, w1, w2a, w2b, x, wf, xb);
        gemm_q<<<(M_DIM / 256) * (N_DIM / 256), 512, 0, stream>>>(xb, wf, b, out);
    } else {
        naive_fallback<<<((long)M_DIM * N_DIM) / 256, 256, 0, stream>>>(
            x, W0, b, w1, w2a, w2b, out);
    }
}